// Round 11
// baseline (1065.461 us; speedup 1.0000x reference)
//
#include <hip/hip_runtime.h>
#include <hip/hip_bf16.h>
#include <hip/hip_cooperative_groups.h>
#include <math.h>

namespace cg = cooperative_groups;

#define D_INNER 32
#define D_STATE 16
#define KDIRS 2
#define BATCH 2
#define CL 32   // scan chunk length (all stages)

// ---------------------------------------------------------------- bicubic
__device__ __forceinline__ float cubic_w(float d) {
    const float a = -0.75f;
    float d2 = d * d, d3 = d2 * d;
    if (d <= 1.0f) return (a + 2.0f) * d3 - (a + 3.0f) * d2 + 1.0f;
    if (d < 2.0f)  return a * d3 - 5.0f * a * d2 + 8.0f * a * d - 4.0f * a;
    return 0.0f;
}

__global__ void upsample_kernel(const float* __restrict__ in, float* __restrict__ out,
                                int h, int w, int H, int W, int total) {
    int i = blockIdx.x * 256 + threadIdx.x;
    if (i >= total) return;
    int ox = i % W; int t = i / W; int oy = t % H; int p = t / H; // p = b*32+d
    const float* ip = in + (size_t)p * h * w;
    float sy = (float)oy * ((float)(h - 1) / (float)(H - 1));
    float sx = (float)ox * ((float)(w - 1) / (float)(W - 1));
    int iy0 = (int)floorf(sy), ix0 = (int)floorf(sx);
    float wy[4], wx[4]; int yi[4], xi[4];
#pragma unroll
    for (int j = 0; j < 4; ++j) {
        int idy = iy0 + j - 1;
        wy[j] = cubic_w(fabsf(sy - (float)idy));
        yi[j] = min(max(idy, 0), h - 1);
        int idx = ix0 + j - 1;
        wx[j] = cubic_w(fabsf(sx - (float)idx));
        xi[j] = min(max(idx, 0), w - 1);
    }
    float acc = 0.f;
#pragma unroll
    for (int jy = 0; jy < 4; ++jy) {
        float rowv = 0.f;
#pragma unroll
        for (int jx = 0; jx < 4; ++jx)
            rowv += wx[jx] * ip[yi[jy] * w + xi[jx]];
        acc += wy[jy] * rowv;
    }
    out[(size_t)p * H * W + (size_t)oy * W + ox] = acc;
}

// ---------------------------------------------------------------- weight transpose (all 4 convs)
__global__ void wtrans_all_kernel(const float* __restrict__ w0, const float* __restrict__ w1,
                                  const float* __restrict__ w2, const float* __restrict__ w3,
                                  float* __restrict__ wT) {
    int i = blockIdx.x * 256 + threadIdx.x;
    if (i >= 442368) return;
    const float* src; int Cin, j;
    if (i < 221184)      { src = w0; Cin = 768; j = i; }
    else if (i < 340992) { src = w1; Cin = 416; j = i - 221184; }
    else if (i < 405504) { src = w2; Cin = 224; j = i - 340992; }
    else                 { src = w3; Cin = 128; j = i - 405504; }
    int oc = j & 31;
    int t = (j >> 5) % 9;
    int ic = j / 288;
    wT[i] = src[((size_t)oc * Cin + ic) * 9 + t];
}

// ---------------------------------------------------------------- stage conv3x3 (512 thr)
__global__ void __launch_bounds__(512) conv_stage_kernel(
        const float* __restrict__ up, const float* __restrict__ feat,
        int cFeat, const float* __restrict__ wT,
        float* __restrict__ partial,
        int H, int W, int tilesX, int ICS) {
    int b = blockIdx.z, s = blockIdx.y;
    int tile = blockIdx.x;
    int tY0 = (tile / tilesX) * 16, tX0 = (tile % tilesX) * 32;
    int tid = threadIdx.x;
    int och = tid >> 8;
    int t256 = tid & 255;
    int row = t256 >> 4, cx = t256 & 15;
    __shared__ float tileS[4][18][35];
    __shared__ float wsh[4][9][32];
    float acc[32];
#pragma unroll
    for (int i = 0; i < 32; ++i) acc[i] = 0.f;
    int icg0 = s * ICS;
    size_t HW = (size_t)H * W;
    for (int icb = 0; icb < ICS; icb += 4) {
        for (int idx = tid; idx < 4 * 612; idx += 512) {
            int ict = idx / 612, rem = idx - ict * 612;
            int r = rem / 34, c = rem - r * 34;
            int icg = icg0 + icb + ict;
            const float* src = (icg < 32)
                ? up + ((size_t)b * 32 + icg) * HW
                : feat + ((size_t)b * cFeat + (icg - 32)) * HW;
            int gy = tY0 + r - 1, gx = tX0 + c - 1;
            tileS[ict][r][c] = (gy >= 0 && gy < H && gx >= 0 && gx < W)
                               ? src[(size_t)gy * W + gx] : 0.f;
        }
        for (int idx = tid; idx < 1152; idx += 512) {
            int ict = idx / 288, rem = idx - ict * 288;
            int t = rem >> 5, j = rem & 31;
            wsh[ict][t][j] = wT[(size_t)(icg0 + icb + ict) * 288 + t * 32 + j];
        }
        __syncthreads();
#pragma unroll
        for (int ic4 = 0; ic4 < 4; ++ic4) {
            float tv[3][4];
#pragma unroll
            for (int dy = 0; dy < 3; ++dy)
#pragma unroll
                for (int dx = 0; dx < 4; ++dx)
                    tv[dy][dx] = tileS[ic4][row + dy][2 * cx + dx];
#pragma unroll
            for (int t = 0; t < 9; ++t) {
                int ty = t / 3, tx = t % 3;
                float p0 = tv[ty][tx + 0], p1 = tv[ty][tx + 1];
#pragma unroll
                for (int ocg = 0; ocg < 4; ++ocg) {
                    float4 wv = *(const float4*)&wsh[ic4][t][och * 16 + ocg * 4];
                    acc[(ocg * 4 + 0) * 2 + 0] = fmaf(p0, wv.x, acc[(ocg * 4 + 0) * 2 + 0]);
                    acc[(ocg * 4 + 0) * 2 + 1] = fmaf(p1, wv.x, acc[(ocg * 4 + 0) * 2 + 1]);
                    acc[(ocg * 4 + 1) * 2 + 0] = fmaf(p0, wv.y, acc[(ocg * 4 + 1) * 2 + 0]);
                    acc[(ocg * 4 + 1) * 2 + 1] = fmaf(p1, wv.y, acc[(ocg * 4 + 1) * 2 + 1]);
                    acc[(ocg * 4 + 2) * 2 + 0] = fmaf(p0, wv.z, acc[(ocg * 4 + 2) * 2 + 0]);
                    acc[(ocg * 4 + 2) * 2 + 1] = fmaf(p1, wv.z, acc[(ocg * 4 + 2) * 2 + 1]);
                    acc[(ocg * 4 + 3) * 2 + 0] = fmaf(p0, wv.w, acc[(ocg * 4 + 3) * 2 + 0]);
                    acc[(ocg * 4 + 3) * 2 + 1] = fmaf(p1, wv.w, acc[(ocg * 4 + 3) * 2 + 1]);
                }
            }
        }
        __syncthreads();
    }
    int oy = tY0 + row, ox = tX0 + 2 * cx;
    float* pp = partial + ((size_t)(s * BATCH + b) * 32 + och * 16) * HW + (size_t)oy * W + ox;
#pragma unroll
    for (int oc = 0; oc < 16; ++oc)
        *(float2*)(pp + (size_t)oc * HW) = make_float2(acc[oc * 2], acc[oc * 2 + 1]);
}

// ---------------------------------------------------------------- fusion conv3x3 (16x16, 1 px/thread, 16 oc)
__global__ void conv_fus_kernel(const float* __restrict__ feat, int cFeat,
                                const float* __restrict__ wT,
                                float* __restrict__ partial, int ICS) {
    int b = blockIdx.z, s = blockIdx.y;
    int och = blockIdx.x;
    int tid = threadIdx.x;
    int row = tid >> 4, col = tid & 15;
    __shared__ float tileS[4][18][19];
    __shared__ float wsh[4][9][16];
    float acc[16];
#pragma unroll
    for (int i = 0; i < 16; ++i) acc[i] = 0.f;
    int icg0 = s * ICS;
    const int H = 16, W = 16;
    size_t HW = 256;
    for (int icb = 0; icb < ICS; icb += 4) {
        for (int idx = tid; idx < 4 * 324; idx += 256) {
            int ict = idx / 324, rem = idx - ict * 324;
            int r = rem / 18, c = rem - r * 18;
            int icg = icg0 + icb + ict;
            const float* src = feat + ((size_t)b * cFeat + icg) * HW;
            int gy = r - 1, gx = c - 1;
            tileS[ict][r][c] = (gy >= 0 && gy < H && gx >= 0 && gx < W)
                               ? src[(size_t)gy * W + gx] : 0.f;
        }
        for (int idx = tid; idx < 576; idx += 256) {
            int ict = idx / 144, rem = idx - ict * 144;
            int t = rem >> 4, j = rem & 15;
            wsh[ict][t][j] = wT[(size_t)(icg0 + icb + ict) * 288 + t * 32 + och * 16 + j];
        }
        __syncthreads();
#pragma unroll
        for (int ic4 = 0; ic4 < 4; ++ic4) {
            float tv[3][3];
#pragma unroll
            for (int dy = 0; dy < 3; ++dy)
#pragma unroll
                for (int dx = 0; dx < 3; ++dx)
                    tv[dy][dx] = tileS[ic4][row + dy][col + dx];
#pragma unroll
            for (int t = 0; t < 9; ++t) {
                float pv = tv[t / 3][t % 3];
#pragma unroll
                for (int ocg = 0; ocg < 4; ++ocg) {
                    float4 wv = *(const float4*)&wsh[ic4][t][ocg * 4];
                    acc[ocg * 4 + 0] = fmaf(pv, wv.x, acc[ocg * 4 + 0]);
                    acc[ocg * 4 + 1] = fmaf(pv, wv.y, acc[ocg * 4 + 1]);
                    acc[ocg * 4 + 2] = fmaf(pv, wv.z, acc[ocg * 4 + 2]);
                    acc[ocg * 4 + 3] = fmaf(pv, wv.w, acc[ocg * 4 + 3]);
                }
            }
        }
        __syncthreads();
    }
    float* pp = partial + ((size_t)(s * BATCH + b) * 32 + och * 16) * HW + (size_t)row * W + col;
#pragma unroll
    for (int oc = 0; oc < 16; ++oc)
        pp[(size_t)oc * HW] = acc[oc];
}

__global__ void conv_reduce_kernel(const float* __restrict__ partial, const float* __restrict__ bias,
                                   float* __restrict__ out, int S, size_t planeTotal, int HW) {
    size_t i = (size_t)blockIdx.x * 256 + threadIdx.x;
    float s = bias[(i / (size_t)HW) & 31];
    for (int ss = 0; ss < S; ++ss) s += partial[(size_t)ss * planeTotal + i];
    out[i] = s;
}

// ---------------------------------------------------------------- fused reduce(+bias) + transpose
__global__ void __launch_bounds__(1024) reduce_transpose_kernel(
        const float* __restrict__ partial, const float* __restrict__ bias,
        float* __restrict__ xbuf, float* __restrict__ xT,
        int S, int H, int W, int tilesX) {
    __shared__ float t[32][33];
    int p = blockIdx.y;
    int tile = blockIdx.x;
    int tx = tile % tilesX, ty = tile / tilesX;
    int tid = threadIdx.x;
    int c = tid & 31, r = tid >> 5;
    size_t HW = (size_t)H * W;
    size_t planeTotal = (size_t)BATCH * 32 * HW;
    size_t off = (size_t)p * HW + (size_t)(ty * 32 + r) * W + tx * 32 + c;
    float s = bias[p & 31];
    for (int ss = 0; ss < S; ++ss) s += partial[(size_t)ss * planeTotal + off];
    t[r][c] = s;
    xbuf[off] = s;
    __syncthreads();
    xT[(size_t)p * HW + (size_t)(tx * 32 + r) * H + ty * 32 + c] = t[c][r];
}

// ================================================================ phase bodies

__device__ __forceinline__ void proj_body(
        int k, int b, int l0, int tid,
        const float* __restrict__ x, const float* __restrict__ xT,
        const float* __restrict__ xpw, const float* __restrict__ dtw,
        const float* __restrict__ dtb,
        float* __restrict__ delta, float* __restrict__ Bm, float* __restrict__ Cm,
        int L, float* xsA, float* dtsS, float* wxpS, float* wdtS, float* bdtS) {
    int li = tid & 63, cgi = tid >> 6;
    for (int idx = tid; idx < 2048; idx += 256) wxpS[idx] = xpw[k * 2048 + idx];
    for (int idx = tid; idx < 1024; idx += 256) wdtS[idx] = dtw[k * 1024 + idx];
    if (tid < 32) bdtS[tid] = dtb[k * 32 + tid];
    const float* u = (k == 0 ? x : xT) + (size_t)b * D_INNER * L + l0;
    for (int idx = tid; idx < 2048; idx += 256) {
        int d = idx >> 6, l = idx & 63;
        xsA[d * 66 + l] = u[(size_t)d * L + l];
    }
    __syncthreads();
    float xr[32];
#pragma unroll
    for (int d = 0; d < 32; ++d) xr[d] = xsA[d * 66 + li];
#pragma unroll
    for (int j = 0; j < 8; ++j) {
        int c = cgi * 8 + j;
        float s = 0.f;
#pragma unroll
        for (int d4 = 0; d4 < 8; ++d4) {
            float4 wv = *(const float4*)&wxpS[c * 32 + d4 * 4];
            s = fmaf(wv.x, xr[d4 * 4 + 0], s);
            s = fmaf(wv.y, xr[d4 * 4 + 1], s);
            s = fmaf(wv.z, xr[d4 * 4 + 2], s);
            s = fmaf(wv.w, xr[d4 * 4 + 3], s);
        }
        dtsS[c * 66 + li] = s;
    }
    __syncthreads();
    {
        float bv[4], cvv[4];
#pragma unroll
        for (int j = 0; j < 4; ++j) {
            int nB = 32 + cgi * 4 + j, nC = 48 + cgi * 4 + j;
            float sB = 0.f, sC = 0.f;
#pragma unroll
            for (int d4 = 0; d4 < 8; ++d4) {
                float4 wB = *(const float4*)&wxpS[nB * 32 + d4 * 4];
                float4 wC = *(const float4*)&wxpS[nC * 32 + d4 * 4];
                sB = fmaf(wB.x, xr[d4 * 4 + 0], sB); sC = fmaf(wC.x, xr[d4 * 4 + 0], sC);
                sB = fmaf(wB.y, xr[d4 * 4 + 1], sB); sC = fmaf(wC.y, xr[d4 * 4 + 1], sC);
                sB = fmaf(wB.z, xr[d4 * 4 + 2], sB); sC = fmaf(wC.z, xr[d4 * 4 + 2], sC);
                sB = fmaf(wB.w, xr[d4 * 4 + 3], sB); sC = fmaf(wC.w, xr[d4 * 4 + 3], sC);
            }
            bv[j] = sB; cvv[j] = sC;
        }
        size_t base16 = ((size_t)(b * KDIRS + k) * L + l0 + li) * 16 + cgi * 4;
        *(float4*)(Bm + base16) = make_float4(bv[0], bv[1], bv[2], bv[3]);
        *(float4*)(Cm + base16) = make_float4(cvv[0], cvv[1], cvv[2], cvv[3]);
    }
    float dr[32];
#pragma unroll
    for (int r = 0; r < 32; ++r) dr[r] = dtsS[r * 66 + li];
    size_t dbase = (((size_t)b * KDIRS + k) * D_INNER) * L + l0 + li;
#pragma unroll
    for (int j = 0; j < 8; ++j) {
        int dd = cgi * 8 + j;
        float s = bdtS[dd];
#pragma unroll
        for (int r4 = 0; r4 < 8; ++r4) {
            float4 wv = *(const float4*)&wdtS[dd * 32 + r4 * 4];
            s = fmaf(wv.x, dr[r4 * 4 + 0], s);
            s = fmaf(wv.y, dr[r4 * 4 + 1], s);
            s = fmaf(wv.z, dr[r4 * 4 + 2], s);
            s = fmaf(wv.w, dr[r4 * 4 + 3], s);
        }
        float sp = (s > 0.f) ? (s + log1pf(expf(-s))) : log1pf(expf(s));
        delta[dbase + (size_t)dd * L] = sp;
    }
}

__device__ __forceinline__ void pass1_body(
        int idx, const float* __restrict__ x, const float* __restrict__ xT,
        const float* __restrict__ delta, const float* __restrict__ Bm,
        const float* __restrict__ A_logs,
        float* __restrict__ Ac, float* __restrict__ Sc, int L, int C, int CLOG) {
    int c = idx & (C - 1);
    int gd = idx >> CLOG;
    int d = gd & 31, bk = gd >> 5;
    int b = gd >> 6;
    int l0 = c * CL;
    const float* uptr = ((bk & 1) == 0 ? x : xT) + ((size_t)b * D_INNER + d) * L + l0;
    const float* dp = delta + (size_t)gd * L + l0;
    const float4* Bp4 = (const float4*)(Bm + ((size_t)bk * L + l0) * 16);
    const float* Ap = A_logs + (size_t)(gd & 63) * 16;
    float Av[16], h[16];
#pragma unroll
    for (int n = 0; n < 16; ++n) { Av[n] = -__expf(Ap[n]); h[n] = 0.f; }
    float sumdl = 0.f;
    for (int j = 0; j < CL; j += 4) {
        float4 dv = *(const float4*)(dp + j);
        float4 uv = *(const float4*)(uptr + j);
#pragma unroll
        for (int e = 0; e < 4; ++e) {
            float dl = e == 0 ? dv.x : e == 1 ? dv.y : e == 2 ? dv.z : dv.w;
            float ul = e == 0 ? uv.x : e == 1 ? uv.y : e == 2 ? uv.z : uv.w;
            float du = dl * ul;
            sumdl += dl;
            const float4* Bp = Bp4 + (size_t)(j + e) * 4;
            float4 B0 = Bp[0], B1 = Bp[1], B2 = Bp[2], B3 = Bp[3];
#define STEP1(nn, bb) { float a = __expf(dl * Av[nn]); h[nn] = fmaf(a, h[nn], du * (bb)); }
            STEP1(0, B0.x) STEP1(1, B0.y) STEP1(2, B0.z) STEP1(3, B0.w)
            STEP1(4, B1.x) STEP1(5, B1.y) STEP1(6, B1.z) STEP1(7, B1.w)
            STEP1(8, B2.x) STEP1(9, B2.y) STEP1(10, B2.z) STEP1(11, B2.w)
            STEP1(12, B3.x) STEP1(13, B3.y) STEP1(14, B3.z) STEP1(15, B3.w)
#undef STEP1
        }
    }
#pragma unroll
    for (int n = 0; n < 16; ++n) {
        size_t o = (size_t)(gd * 16 + n) * C + c;
        Ac[o] = __expf(Av[n] * sumdl);
        Sc[o] = h[n];
    }
}

__device__ __forceinline__ void stitch_body(
        int t, const float* __restrict__ Ac, const float* __restrict__ Sc,
        float* __restrict__ Hs, int C) {
    const float4* Ap = (const float4*)(Ac + (size_t)t * C);
    const float4* Sp = (const float4*)(Sc + (size_t)t * C);
    int gd = t >> 4, n = t & 15;
    float* Ho = Hs + (size_t)gd * C * 16 + n;
    float h = 0.f;
    for (int c4 = 0; c4 < (C >> 2); ++c4) {
        float4 a = Ap[c4], s = Sp[c4];
        Ho[(size_t)(c4 * 4 + 0) * 16] = h; h = fmaf(a.x, h, s.x);
        Ho[(size_t)(c4 * 4 + 1) * 16] = h; h = fmaf(a.y, h, s.y);
        Ho[(size_t)(c4 * 4 + 2) * 16] = h; h = fmaf(a.z, h, s.z);
        Ho[(size_t)(c4 * 4 + 3) * 16] = h; h = fmaf(a.w, h, s.w);
    }
}

__device__ __forceinline__ void pass2_body(
        int idx, const float* __restrict__ x, const float* __restrict__ xT,
        const float* __restrict__ delta, const float* __restrict__ Bm,
        const float* __restrict__ Cm,
        const float* __restrict__ A_logs, const float* __restrict__ Ds,
        const float* __restrict__ Hs,
        float* __restrict__ ys, int L, int C, int CLOG, int W, int hsh) {
    int c = idx & (C - 1);
    int gd = idx >> CLOG;
    int d = gd & 31, bk = gd >> 5;
    int k = bk & 1, b = gd >> 6;
    int l0 = c * CL;
    const float* uptr = (k == 0 ? x : xT) + ((size_t)b * D_INNER + d) * L + l0;
    const float* dp = delta + (size_t)gd * L + l0;
    const float4* Bp4 = (const float4*)(Bm + ((size_t)bk * L + l0) * 16);
    const float4* Cp4 = (const float4*)(Cm + ((size_t)bk * L + l0) * 16);
    const float* Ap = A_logs + (size_t)(gd & 63) * 16;
    float Av[16], h[16];
#pragma unroll
    for (int n = 0; n < 16; ++n) Av[n] = -__expf(Ap[n]);
    const float4* Hp = (const float4*)(Hs + ((size_t)gd * C + c) * 16);
    float4 h0 = Hp[0], h1 = Hp[1], h2 = Hp[2], h3 = Hp[3];
    h[0] = h0.x; h[1] = h0.y; h[2] = h0.z; h[3] = h0.w;
    h[4] = h1.x; h[5] = h1.y; h[6] = h1.z; h[7] = h1.w;
    h[8] = h2.x; h[9] = h2.y; h[10] = h2.z; h[11] = h2.w;
    h[12] = h3.x; h[13] = h3.y; h[14] = h3.z; h[15] = h3.w;
    float Dval = Ds[gd & 63];
    float* yout = ys + (size_t)gd * L;
    int Hm1 = (1 << hsh) - 1;
    for (int j = 0; j < CL; j += 4) {
        float4 dv = *(const float4*)(dp + j);
        float4 uv = *(const float4*)(uptr + j);
        float yb[4];
#pragma unroll
        for (int e = 0; e < 4; ++e) {
            float dl = e == 0 ? dv.x : e == 1 ? dv.y : e == 2 ? dv.z : dv.w;
            float ul = e == 0 ? uv.x : e == 1 ? uv.y : e == 2 ? uv.z : uv.w;
            float du = dl * ul;
            const float4* Bp = Bp4 + (size_t)(j + e) * 4;
            const float4* Cp = Cp4 + (size_t)(j + e) * 4;
            float4 B0 = Bp[0], B1 = Bp[1], B2 = Bp[2], B3 = Bp[3];
            float4 C0 = Cp[0], C1 = Cp[1], C2 = Cp[2], C3 = Cp[3];
            float y = 0.f;
#define STEP(nn, bb, cc) { float a = __expf(dl * Av[nn]); h[nn] = fmaf(a, h[nn], du * (bb)); y = fmaf(h[nn], (cc), y); }
            STEP(0, B0.x, C0.x) STEP(1, B0.y, C0.y) STEP(2, B0.z, C0.z) STEP(3, B0.w, C0.w)
            STEP(4, B1.x, C1.x) STEP(5, B1.y, C1.y) STEP(6, B1.z, C1.z) STEP(7, B1.w, C1.w)
            STEP(8, B2.x, C2.x) STEP(9, B2.y, C2.y) STEP(10, B2.z, C2.z) STEP(11, B2.w, C2.w)
            STEP(12, B3.x, C3.x) STEP(13, B3.y, C3.y) STEP(14, B3.z, C3.z) STEP(15, B3.w, C3.w)
#undef STEP
            y = fmaf(Dval, ul, y);
            if (k == 0) {
                yb[e] = y;
            } else {
                int l = l0 + j + e;
                yout[(l & Hm1) * W + (l >> hsh)] = y;
            }
        }
        if (k == 0)
            *(float4*)(yout + l0 + j) = make_float4(yb[0], yb[1], yb[2], yb[3]);
    }
}

__device__ __forceinline__ void combine_body(
        int i, const float* __restrict__ ys, const float* __restrict__ g,
        const float* __restrict__ beta, float* __restrict__ outp, int L) {
    int b = i / L;
    int l = i - b * L;
    const float* y0 = ys + ((size_t)b * KDIRS + 0) * D_INNER * L + l;
    const float* y1 = ys + ((size_t)b * KDIRS + 1) * D_INNER * L + l;
    float v[32]; float sum = 0.f;
#pragma unroll
    for (int d = 0; d < 32; ++d) {
        float t = y0[(size_t)d * L] + y1[(size_t)d * L];
        v[d] = t; sum += t;
    }
    float mu = sum * (1.0f / 32.0f);
    float var = 0.f;
#pragma unroll
    for (int d = 0; d < 32; ++d) { float t = v[d] - mu; var += t * t; }
    var *= (1.0f / 32.0f);
    float inv = 1.0f / sqrtf(var + 1e-5f);
#pragma unroll
    for (int d = 0; d < 32; ++d)
        outp[((size_t)b * D_INNER + d) * L + l] = (v[d] - mu) * inv * g[d] + beta[d];
}

// ---------------------------------------------------------------- cooperative mega kernel
// __launch_bounds__(256,4): cap 128 VGPR -> 4 blocks/CU co-resident (LDS 29.3KB*4=117KB).
__global__ void __launch_bounds__(256, 4) ssm_mega_kernel(
        const float* __restrict__ x, const float* __restrict__ xT,
        const float* __restrict__ xpw, const float* __restrict__ dtw,
        const float* __restrict__ dtb,
        float* __restrict__ delta, float* __restrict__ Bm, float* __restrict__ Cm,
        const float* __restrict__ A_logs, const float* __restrict__ Ds,
        float* __restrict__ Ac, float* __restrict__ Sc, float* __restrict__ Hst,
        float* __restrict__ ys, const float* __restrict__ lng, const float* __restrict__ lnb,
        float* __restrict__ outp,
        int L, int C, int CLOG, int W, int hsh) {
    cg::grid_group gridg = cg::this_grid();
    int tid = threadIdx.x;
    int NB = gridDim.x;
    __shared__ float xsA[32 * 66];
    __shared__ float dtsS[32 * 66];
    __shared__ float wxpS[2048];
    __shared__ float wdtS[1024];
    __shared__ float bdtS[32];

    // phase P: projections. units = (L/64)*KDIRS*BATCH = 2C
    int unitsP = C << 1;
    for (int unit = blockIdx.x; unit < unitsP; unit += NB) {
        __syncthreads();
        int lb = unit & ((C >> 1) - 1);
        int rest = unit >> (CLOG - 1);
        int k = rest & 1, b = rest >> 1;
        proj_body(k, b, lb * 64, tid, x, xT, xpw, dtw, dtb, delta, Bm, Cm, L,
                  xsA, dtsS, wxpS, wdtS, bdtS);
    }
    gridg.sync();

    // phase 1: C*128 threads
    for (int idx = blockIdx.x * 256 + tid; idx < (C << 7); idx += NB * 256)
        pass1_body(idx, x, xT, delta, Bm, A_logs, Ac, Sc, L, C, CLOG);
    gridg.sync();

    // phase S: 2048 threads
    for (int t = blockIdx.x * 256 + tid; t < 2048; t += NB * 256)
        stitch_body(t, Ac, Sc, Hst, C);
    gridg.sync();

    // phase 2
    for (int idx = blockIdx.x * 256 + tid; idx < (C << 7); idx += NB * 256)
        pass2_body(idx, x, xT, delta, Bm, Cm, A_logs, Ds, Hst, ys, L, C, CLOG, W, hsh);
    gridg.sync();

    // phase C: 2L threads
    for (int i = blockIdx.x * 256 + tid; i < 2 * L; i += NB * 256)
        combine_body(i, ys, lng, lnb, outp, L);
}

// ---------------------------------------------------------------- standalone fallback kernels
__global__ void __launch_bounds__(256) proj_kernel(
        const float* __restrict__ x, const float* __restrict__ xT,
        const float* __restrict__ xpw, const float* __restrict__ dtw,
        const float* __restrict__ dtb,
        float* __restrict__ delta, float* __restrict__ Bm, float* __restrict__ Cm, int L) {
    __shared__ float xsA[32 * 66];
    __shared__ float dtsS[32 * 66];
    __shared__ float wxpS[2048];
    __shared__ float wdtS[1024];
    __shared__ float bdtS[32];
    proj_body(blockIdx.y, blockIdx.z, blockIdx.x * 64, threadIdx.x,
              x, xT, xpw, dtw, dtb, delta, Bm, Cm, L, xsA, dtsS, wxpS, wdtS, bdtS);
}

__global__ void __launch_bounds__(256) scan_pass1_k(
        const float* __restrict__ x, const float* __restrict__ xT,
        const float* __restrict__ delta, const float* __restrict__ Bm,
        const float* __restrict__ A_logs,
        float* __restrict__ Ac, float* __restrict__ Sc, int L, int C, int CLOG) {
    pass1_body(blockIdx.x * 256 + threadIdx.x, x, xT, delta, Bm, A_logs, Ac, Sc, L, C, CLOG);
}

__global__ void __launch_bounds__(256) scan_stitch_k(
        const float* __restrict__ Ac, const float* __restrict__ Sc,
        float* __restrict__ Hs, int C) {
    stitch_body(blockIdx.x * 256 + threadIdx.x, Ac, Sc, Hs, C);
}

__global__ void __launch_bounds__(256) scan_pass2_k(
        const float* __restrict__ x, const float* __restrict__ xT,
        const float* __restrict__ delta, const float* __restrict__ Bm,
        const float* __restrict__ Cm,
        const float* __restrict__ A_logs, const float* __restrict__ Ds,
        const float* __restrict__ Hs,
        float* __restrict__ ys, int L, int C, int CLOG, int W, int hsh) {
    pass2_body(blockIdx.x * 256 + threadIdx.x, x, xT, delta, Bm, Cm, A_logs, Ds, Hs,
               ys, L, C, CLOG, W, hsh);
}

__global__ void combine_ln_kernel(const float* __restrict__ ys, const float* __restrict__ g,
                                  const float* __restrict__ beta, float* __restrict__ outp, int L) {
    combine_body(blockIdx.y * L + blockIdx.x * 256 + threadIdx.x, ys, g, beta, outp, L);
}

// ---------------------------------------------------------------- host
extern "C" void kernel_launch(void* const* d_in, const int* in_sizes, int n_in,
                              void* d_out, int out_size, void* d_ws, size_t ws_size,
                              hipStream_t stream) {
    const float* out0 = (const float*)d_in[0];
    const float* out1 = (const float*)d_in[1];
    const float* out2 = (const float*)d_in[2];
    const float* out3 = (const float*)d_in[3];
    const float* cw[4] = {(const float*)d_in[4], (const float*)d_in[6],
                          (const float*)d_in[8], (const float*)d_in[10]};
    const float* cb[4] = {(const float*)d_in[5], (const float*)d_in[7],
                          (const float*)d_in[9], (const float*)d_in[11]};
    const float* xpw    = (const float*)d_in[12];
    const float* dtw    = (const float*)d_in[13];
    const float* dtb    = (const float*)d_in[14];
    const float* A_logs = (const float*)d_in[15];
    const float* Ds     = (const float*)d_in[16];
    const float* ln_g   = (const float*)d_in[17];
    const float* ln_b   = (const float*)d_in[18];

    const size_t MF = 1u << 20;
    float* ws    = (float*)d_ws;
    float* fus   = ws;
    float* Hst   = ws + 1 * MF;
    float* up    = ws + 2 * MF;
    float* xbuf  = ws + 3 * MF;
    float* xTbuf = ws + 4 * MF;
    float* delta = ws + 5 * MF;
    float* Bm    = ws + 7 * MF;
    float* Cm    = ws + 8 * MF;
    float* ysbuf = ws + 9 * MF;
    float* Ac    = ws + 11 * MF;
    float* Sc    = ws + 12 * MF;
    float* wT    = ws + 13 * MF;
    float* partial = ws + 14 * MF;

    wtrans_all_kernel<<<(442368 + 255) / 256, 256, 0, stream>>>(cw[0], cw[1], cw[2], cw[3], wT);
    float* wT_f  = wT;
    float* wT_s1 = wT + 221184;
    float* wT_s2 = wT + 340992;
    float* wT_s3 = wT + 405504;

    {
        int Cin = 768, ICS = 8, S = Cin / ICS;
        conv_fus_kernel<<<dim3(2, S, BATCH), 256, 0, stream>>>(out3, Cin, wT_f, partial, ICS);
        size_t planeTotal = (size_t)BATCH * 32 * 256;
        conv_reduce_kernel<<<planeTotal / 256, 256, 0, stream>>>(
            partial, cb[0], fus, S, planeTotal, 256);
    }

    // co-residency capacity for the mega kernel (pure host query, capture-safe)
    int blocksPerCU = 0;
    if (hipOccupancyMaxActiveBlocksPerMultiprocessor(&blocksPerCU,
            (const void*)ssm_mega_kernel, 256, 0) != hipSuccess || blocksPerCU < 1)
        blocksPerCU = 0;
    int maxCoop = blocksPerCU * 256;

    struct Stage { int h, w, H, W, Cf, ICS, hsh; const float* feat; const float* wt; const float* b3; };
    Stage st[3] = {
        {16, 16,  32,  32, 384,  8, 5, out2, wT_s1, cb[1]},
        {32, 32,  64,  64, 192,  8, 6, out1, wT_s2, cb[2]},
        {64, 64, 128, 128,  96, 16, 7, out0, wT_s3, cb[3]},
    };

    for (int i = 0; i < 3; ++i) {
        int H = st[i].H, Wv = st[i].W;
        int L = H * Wv;
        int h = st[i].h, w = st[i].w;
        int total = BATCH * 32 * H * Wv;
        upsample_kernel<<<total / 256, 256, 0, stream>>>(fus, up, h, w, H, Wv, total);

        int Cin = 32 + st[i].Cf;
        int ICS = st[i].ICS, S = Cin / ICS;
        int tilesX = Wv / 32, tiles = (H / 16) * tilesX;
        conv_stage_kernel<<<dim3(tiles, S, BATCH), 512, 0, stream>>>(
            up, st[i].feat, st[i].Cf, st[i].wt, partial, H, Wv, tilesX, ICS);

        reduce_transpose_kernel<<<dim3((H / 32) * tilesX, BATCH * 32), 1024, 0, stream>>>(
            partial, cb[i + 1], xbuf, xTbuf, S, H, Wv, tilesX);

        int C = L / CL;
        int CLOG = (C == 32) ? 5 : (C == 128) ? 7 : 9;
        int hshv = st[i].hsh;
        float* dst = (i == 2) ? (float*)d_out : fus;

        int G = 2 * C;                 // enough for every phase's widest unit count
        if (G > maxCoop) G = maxCoop;  // clamp to co-residency capacity
        bool megaOK = (G >= 8);        // need at least 2048 threads for stitch in one pass

        hipError_t err = hipErrorUnknown;
        if (megaOK) {
            void* margs[] = {
                (void*)&xbuf, (void*)&xTbuf, (void*)&xpw, (void*)&dtw, (void*)&dtb,
                (void*)&delta, (void*)&Bm, (void*)&Cm, (void*)&A_logs, (void*)&Ds,
                (void*)&Ac, (void*)&Sc, (void*)&Hst, (void*)&ysbuf,
                (void*)&ln_g, (void*)&ln_b, (void*)&dst,
                (void*)&L, (void*)&C, (void*)&CLOG, (void*)&Wv, (void*)&hshv
            };
            err = hipLaunchCooperativeKernel((void*)ssm_mega_kernel,
                                             dim3(G), dim3(256), margs, 0, stream);
        }
        if (err != hipSuccess) {
            // fallback: separate dispatches (r8-proven path)
            proj_kernel<<<dim3(L / 64, KDIRS, BATCH), 256, 0, stream>>>(
                xbuf, xTbuf, xpw, dtw, dtb, delta, Bm, Cm, L);
            int passBlocks = (128 * C) / 256;
            scan_pass1_k<<<passBlocks, 256, 0, stream>>>(xbuf, xTbuf, delta, Bm, A_logs,
                                                         Ac, Sc, L, C, CLOG);
            scan_stitch_k<<<8, 256, 0, stream>>>(Ac, Sc, Hst, C);
            scan_pass2_k<<<passBlocks, 256, 0, stream>>>(xbuf, xTbuf, delta, Bm, Cm, A_logs,
                                                         Ds, Hst, ysbuf, L, C, CLOG, Wv, hshv);
            combine_ln_kernel<<<dim3(L / 256, BATCH), 256, 0, stream>>>(ysbuf, ln_g, ln_b, dst, L);
        }
    }
}

// Round 12
// 582.951 us; speedup vs baseline: 1.8277x; 1.8277x over previous
//
#include <hip/hip_runtime.h>
#include <hip/hip_bf16.h>
#include <math.h>

#define D_INNER 32
#define D_STATE 16
#define KDIRS 2
#define BATCH 2
#define CL 32   // scan chunk length (all stages)

// ---------------------------------------------------------------- bicubic
__device__ __forceinline__ float cubic_w(float d) {
    const float a = -0.75f;
    float d2 = d * d, d3 = d2 * d;
    if (d <= 1.0f) return (a + 2.0f) * d3 - (a + 3.0f) * d2 + 1.0f;
    if (d < 2.0f)  return a * d3 - 5.0f * a * d2 + 8.0f * a * d - 4.0f * a;
    return 0.0f;
}

__global__ void upsample_kernel(const float* __restrict__ in, float* __restrict__ out,
                                int h, int w, int H, int W, int total) {
    int i = blockIdx.x * 256 + threadIdx.x;
    if (i >= total) return;
    int ox = i % W; int t = i / W; int oy = t % H; int p = t / H; // p = b*32+d
    const float* ip = in + (size_t)p * h * w;
    float sy = (float)oy * ((float)(h - 1) / (float)(H - 1));
    float sx = (float)ox * ((float)(w - 1) / (float)(W - 1));
    int iy0 = (int)floorf(sy), ix0 = (int)floorf(sx);
    float wy[4], wx[4]; int yi[4], xi[4];
#pragma unroll
    for (int j = 0; j < 4; ++j) {
        int idy = iy0 + j - 1;
        wy[j] = cubic_w(fabsf(sy - (float)idy));
        yi[j] = min(max(idy, 0), h - 1);
        int idx = ix0 + j - 1;
        wx[j] = cubic_w(fabsf(sx - (float)idx));
        xi[j] = min(max(idx, 0), w - 1);
    }
    float acc = 0.f;
#pragma unroll
    for (int jy = 0; jy < 4; ++jy) {
        float rowv = 0.f;
#pragma unroll
        for (int jx = 0; jx < 4; ++jx)
            rowv += wx[jx] * ip[yi[jy] * w + xi[jx]];
        acc += wy[jy] * rowv;
    }
    out[(size_t)p * H * W + (size_t)oy * W + ox] = acc;
}

// ---------------------------------------------------------------- weight transpose (all 4 convs)
__global__ void wtrans_all_kernel(const float* __restrict__ w0, const float* __restrict__ w1,
                                  const float* __restrict__ w2, const float* __restrict__ w3,
                                  float* __restrict__ wT) {
    int i = blockIdx.x * 256 + threadIdx.x;
    if (i >= 442368) return;
    const float* src; int Cin, j;
    if (i < 221184)      { src = w0; Cin = 768; j = i; }
    else if (i < 340992) { src = w1; Cin = 416; j = i - 221184; }
    else if (i < 405504) { src = w2; Cin = 224; j = i - 340992; }
    else                 { src = w3; Cin = 128; j = i - 405504; }
    int oc = j & 31;
    int t = (j >> 5) % 9;
    int ic = j / 288;
    wT[i] = src[((size_t)oc * Cin + ic) * 9 + t];
}

// ---------------------------------------------------------------- stage conv3x3 (512 thr, both oc halves)
__global__ void __launch_bounds__(512) conv_stage_kernel(
        const float* __restrict__ up, const float* __restrict__ feat,
        int cFeat, const float* __restrict__ wT,
        float* __restrict__ partial,
        int H, int W, int tilesX, int ICS) {
    int b = blockIdx.z, s = blockIdx.y;
    int tile = blockIdx.x;
    int tY0 = (tile / tilesX) * 16, tX0 = (tile % tilesX) * 32;
    int tid = threadIdx.x;
    int och = tid >> 8;
    int t256 = tid & 255;
    int row = t256 >> 4, cx = t256 & 15;
    __shared__ float tileS[4][18][35];
    __shared__ float wsh[4][9][32];
    float acc[32];
#pragma unroll
    for (int i = 0; i < 32; ++i) acc[i] = 0.f;
    int icg0 = s * ICS;
    size_t HW = (size_t)H * W;
    for (int icb = 0; icb < ICS; icb += 4) {
        for (int idx = tid; idx < 4 * 612; idx += 512) {
            int ict = idx / 612, rem = idx - ict * 612;
            int r = rem / 34, c = rem - r * 34;
            int icg = icg0 + icb + ict;
            const float* src = (icg < 32)
                ? up + ((size_t)b * 32 + icg) * HW
                : feat + ((size_t)b * cFeat + (icg - 32)) * HW;
            int gy = tY0 + r - 1, gx = tX0 + c - 1;
            tileS[ict][r][c] = (gy >= 0 && gy < H && gx >= 0 && gx < W)
                               ? src[(size_t)gy * W + gx] : 0.f;
        }
        for (int idx = tid; idx < 1152; idx += 512) {
            int ict = idx / 288, rem = idx - ict * 288;
            int t = rem >> 5, j = rem & 31;
            wsh[ict][t][j] = wT[(size_t)(icg0 + icb + ict) * 288 + t * 32 + j];
        }
        __syncthreads();
#pragma unroll
        for (int ic4 = 0; ic4 < 4; ++ic4) {
            float tv[3][4];
#pragma unroll
            for (int dy = 0; dy < 3; ++dy)
#pragma unroll
                for (int dx = 0; dx < 4; ++dx)
                    tv[dy][dx] = tileS[ic4][row + dy][2 * cx + dx];
#pragma unroll
            for (int t = 0; t < 9; ++t) {
                int ty = t / 3, tx = t % 3;
                float p0 = tv[ty][tx + 0], p1 = tv[ty][tx + 1];
#pragma unroll
                for (int ocg = 0; ocg < 4; ++ocg) {
                    float4 wv = *(const float4*)&wsh[ic4][t][och * 16 + ocg * 4];
                    acc[(ocg * 4 + 0) * 2 + 0] = fmaf(p0, wv.x, acc[(ocg * 4 + 0) * 2 + 0]);
                    acc[(ocg * 4 + 0) * 2 + 1] = fmaf(p1, wv.x, acc[(ocg * 4 + 0) * 2 + 1]);
                    acc[(ocg * 4 + 1) * 2 + 0] = fmaf(p0, wv.y, acc[(ocg * 4 + 1) * 2 + 0]);
                    acc[(ocg * 4 + 1) * 2 + 1] = fmaf(p1, wv.y, acc[(ocg * 4 + 1) * 2 + 1]);
                    acc[(ocg * 4 + 2) * 2 + 0] = fmaf(p0, wv.z, acc[(ocg * 4 + 2) * 2 + 0]);
                    acc[(ocg * 4 + 2) * 2 + 1] = fmaf(p1, wv.z, acc[(ocg * 4 + 2) * 2 + 1]);
                    acc[(ocg * 4 + 3) * 2 + 0] = fmaf(p0, wv.w, acc[(ocg * 4 + 3) * 2 + 0]);
                    acc[(ocg * 4 + 3) * 2 + 1] = fmaf(p1, wv.w, acc[(ocg * 4 + 3) * 2 + 1]);
                }
            }
        }
        __syncthreads();
    }
    int oy = tY0 + row, ox = tX0 + 2 * cx;
    float* pp = partial + ((size_t)(s * BATCH + b) * 32 + och * 16) * HW + (size_t)oy * W + ox;
#pragma unroll
    for (int oc = 0; oc < 16; ++oc)
        *(float2*)(pp + (size_t)oc * HW) = make_float2(acc[oc * 2], acc[oc * 2 + 1]);
}

// ---------------------------------------------------------------- fusion conv3x3 (16x16, 1 px/thread, 16 oc)
__global__ void conv_fus_kernel(const float* __restrict__ feat, int cFeat,
                                const float* __restrict__ wT,
                                float* __restrict__ partial, int ICS) {
    int b = blockIdx.z, s = blockIdx.y;
    int och = blockIdx.x;
    int tid = threadIdx.x;
    int row = tid >> 4, col = tid & 15;
    __shared__ float tileS[4][18][19];
    __shared__ float wsh[4][9][16];
    float acc[16];
#pragma unroll
    for (int i = 0; i < 16; ++i) acc[i] = 0.f;
    int icg0 = s * ICS;
    const int H = 16, W = 16;
    size_t HW = 256;
    for (int icb = 0; icb < ICS; icb += 4) {
        for (int idx = tid; idx < 4 * 324; idx += 256) {
            int ict = idx / 324, rem = idx - ict * 324;
            int r = rem / 18, c = rem - r * 18;
            int icg = icg0 + icb + ict;
            const float* src = feat + ((size_t)b * cFeat + icg) * HW;
            int gy = r - 1, gx = c - 1;
            tileS[ict][r][c] = (gy >= 0 && gy < H && gx >= 0 && gx < W)
                               ? src[(size_t)gy * W + gx] : 0.f;
        }
        for (int idx = tid; idx < 576; idx += 256) {
            int ict = idx / 144, rem = idx - ict * 144;
            int t = rem >> 4, j = rem & 15;
            wsh[ict][t][j] = wT[(size_t)(icg0 + icb + ict) * 288 + t * 32 + och * 16 + j];
        }
        __syncthreads();
#pragma unroll
        for (int ic4 = 0; ic4 < 4; ++ic4) {
            float tv[3][3];
#pragma unroll
            for (int dy = 0; dy < 3; ++dy)
#pragma unroll
                for (int dx = 0; dx < 3; ++dx)
                    tv[dy][dx] = tileS[ic4][row + dy][col + dx];
#pragma unroll
            for (int t = 0; t < 9; ++t) {
                float pv = tv[t / 3][t % 3];
#pragma unroll
                for (int ocg = 0; ocg < 4; ++ocg) {
                    float4 wv = *(const float4*)&wsh[ic4][t][ocg * 4];
                    acc[ocg * 4 + 0] = fmaf(pv, wv.x, acc[ocg * 4 + 0]);
                    acc[ocg * 4 + 1] = fmaf(pv, wv.y, acc[ocg * 4 + 1]);
                    acc[ocg * 4 + 2] = fmaf(pv, wv.z, acc[ocg * 4 + 2]);
                    acc[ocg * 4 + 3] = fmaf(pv, wv.w, acc[ocg * 4 + 3]);
                }
            }
        }
        __syncthreads();
    }
    float* pp = partial + ((size_t)(s * BATCH + b) * 32 + och * 16) * HW + (size_t)row * W + col;
#pragma unroll
    for (int oc = 0; oc < 16; ++oc)
        pp[(size_t)oc * HW] = acc[oc];
}

__global__ void conv_reduce_kernel(const float* __restrict__ partial, const float* __restrict__ bias,
                                   float* __restrict__ out, int S, size_t planeTotal, int HW) {
    size_t i = (size_t)blockIdx.x * 256 + threadIdx.x;
    float s = bias[(i / (size_t)HW) & 31];
    for (int ss = 0; ss < S; ++ss) s += partial[(size_t)ss * planeTotal + i];
    out[i] = s;
}

// ---------------------------------------------------------------- fused reduce(+bias) + transpose
__global__ void __launch_bounds__(1024) reduce_transpose_kernel(
        const float* __restrict__ partial, const float* __restrict__ bias,
        float* __restrict__ xbuf, float* __restrict__ xT,
        int S, int H, int W, int tilesX) {
    __shared__ float t[32][33];
    int p = blockIdx.y;                        // b*32+oc
    int tile = blockIdx.x;
    int tx = tile % tilesX, ty = tile / tilesX;
    int tid = threadIdx.x;
    int c = tid & 31, r = tid >> 5;
    size_t HW = (size_t)H * W;
    size_t planeTotal = (size_t)BATCH * 32 * HW;
    size_t off = (size_t)p * HW + (size_t)(ty * 32 + r) * W + tx * 32 + c;
    float s = bias[p & 31];
    for (int ss = 0; ss < S; ++ss) s += partial[(size_t)ss * planeTotal + off];
    t[r][c] = s;
    xbuf[off] = s;
    __syncthreads();
    xT[(size_t)p * HW + (size_t)(tx * 32 + r) * H + ty * 32 + c] = t[c][r];
}

// ---------------------------------------------------------------- proj (+softplus) + fused scan pass1
// Block: 64 l-positions x 4 c-groups (256 thr). After computing delta/B in LDS,
// the same block runs pass1 for its two 32-l chunks: 1024 (c,d,n)-chains, 4/thread.
__global__ void __launch_bounds__(256) proj_scan1_kernel(
        const float* __restrict__ x, const float* __restrict__ xT,
        const float* __restrict__ xpw, const float* __restrict__ dtw,
        const float* __restrict__ dtb, const float* __restrict__ A_logs,
        float* __restrict__ delta, float* __restrict__ Bm, float* __restrict__ Cm,
        float* __restrict__ Ac, float* __restrict__ Sc,
        int L, int C) {
    int k = blockIdx.y, b = blockIdx.z;
    int l0 = blockIdx.x * 64;
    int tid = threadIdx.x;
    int li = tid & 63, cgi = tid >> 6;
    __shared__ float xsA[32 * 66];     // u
    __shared__ float dtsS[32 * 66];    // dts, then reused as delta
    __shared__ float bS[16 * 66];      // B rows
    __shared__ float wxpS[2048];
    __shared__ float wdtS[1024];
    __shared__ float bdtS[32];
    for (int idx = tid; idx < 2048; idx += 256) wxpS[idx] = xpw[k * 2048 + idx];
    for (int idx = tid; idx < 1024; idx += 256) wdtS[idx] = dtw[k * 1024 + idx];
    if (tid < 32) bdtS[tid] = dtb[k * 32 + tid];
    const float* u = (k == 0 ? x : xT) + (size_t)b * D_INNER * L + l0;
    for (int idx = tid; idx < 2048; idx += 256) {
        int d = idx >> 6, l = idx & 63;
        xsA[d * 66 + l] = u[(size_t)d * L + l];
    }
    __syncthreads();
    float xr[32];
#pragma unroll
    for (int d = 0; d < 32; ++d) xr[d] = xsA[d * 66 + li];
    // phase A: dts rows cgi*8..+7
#pragma unroll
    for (int j = 0; j < 8; ++j) {
        int c = cgi * 8 + j;
        float s = 0.f;
#pragma unroll
        for (int d4 = 0; d4 < 8; ++d4) {
            float4 wv = *(const float4*)&wxpS[c * 32 + d4 * 4];
            s = fmaf(wv.x, xr[d4 * 4 + 0], s);
            s = fmaf(wv.y, xr[d4 * 4 + 1], s);
            s = fmaf(wv.z, xr[d4 * 4 + 2], s);
            s = fmaf(wv.w, xr[d4 * 4 + 3], s);
        }
        dtsS[c * 66 + li] = s;
    }
    __syncthreads();
    // phase B1: B rows n=cgi*4..+3 and C rows
    {
        float bv[4], cvv[4];
#pragma unroll
        for (int j = 0; j < 4; ++j) {
            int nB = 32 + cgi * 4 + j, nC = 48 + cgi * 4 + j;
            float sB = 0.f, sC = 0.f;
#pragma unroll
            for (int d4 = 0; d4 < 8; ++d4) {
                float4 wB = *(const float4*)&wxpS[nB * 32 + d4 * 4];
                float4 wC = *(const float4*)&wxpS[nC * 32 + d4 * 4];
                sB = fmaf(wB.x, xr[d4 * 4 + 0], sB); sC = fmaf(wC.x, xr[d4 * 4 + 0], sC);
                sB = fmaf(wB.y, xr[d4 * 4 + 1], sB); sC = fmaf(wC.y, xr[d4 * 4 + 1], sC);
                sB = fmaf(wB.z, xr[d4 * 4 + 2], sB); sC = fmaf(wC.z, xr[d4 * 4 + 2], sC);
                sB = fmaf(wB.w, xr[d4 * 4 + 3], sB); sC = fmaf(wC.w, xr[d4 * 4 + 3], sC);
            }
            bv[j] = sB; cvv[j] = sC;
            bS[(cgi * 4 + j) * 66 + li] = sB;
        }
        size_t base16 = ((size_t)(b * KDIRS + k) * L + l0 + li) * 16 + cgi * 4;
        *(float4*)(Bm + base16) = make_float4(bv[0], bv[1], bv[2], bv[3]);
        *(float4*)(Cm + base16) = make_float4(cvv[0], cvv[1], cvv[2], cvv[3]);
    }
    // phase B2: delta rows dd=cgi*8..+7 (read all dts first, then reuse dtsS for delta)
    float dr[32];
#pragma unroll
    for (int r = 0; r < 32; ++r) dr[r] = dtsS[r * 66 + li];
    __syncthreads();
    size_t dbase = (((size_t)b * KDIRS + k) * D_INNER) * L + l0 + li;
#pragma unroll
    for (int j = 0; j < 8; ++j) {
        int dd = cgi * 8 + j;
        float s = bdtS[dd];
#pragma unroll
        for (int r4 = 0; r4 < 8; ++r4) {
            float4 wv = *(const float4*)&wdtS[dd * 32 + r4 * 4];
            s = fmaf(wv.x, dr[r4 * 4 + 0], s);
            s = fmaf(wv.y, dr[r4 * 4 + 1], s);
            s = fmaf(wv.z, dr[r4 * 4 + 2], s);
            s = fmaf(wv.w, dr[r4 * 4 + 3], s);
        }
        float sp = (s > 0.f) ? (s + log1pf(expf(-s))) : log1pf(expf(s));
        delta[dbase + (size_t)dd * L] = sp;
        dtsS[dd * 66 + li] = sp;          // deltaS
    }
    __syncthreads();
    // fused pass1: chains (cl in {0,1}) x 32 d x 16 n, 4 per thread
    int gdbase = (b * KDIRS + k) * D_INNER;
    int c0 = l0 >> 5;
#pragma unroll
    for (int iter = 0; iter < 4; ++iter) {
        int chain = iter * 256 + tid;
        int cl = chain >> 9;
        int rem = chain & 511;
        int d = rem >> 4, n = rem & 15;
        float Av = -__expf(A_logs[(k * D_INNER + d) * 16 + n]);
        float h = 0.f, sumdl = 0.f;
        const float* dS = dtsS + d * 66 + cl * 32;
        const float* uS = xsA + d * 66 + cl * 32;
        const float* BS = bS + n * 66 + cl * 32;
#pragma unroll
        for (int ll = 0; ll < 32; ++ll) {
            float dl = dS[ll], ul = uS[ll], Bl = BS[ll];
            h = fmaf(__expf(dl * Av), h, dl * ul * Bl);
            sumdl += dl;
        }
        size_t o = (size_t)((gdbase + d) * 16 + n) * C + (c0 + cl);
        Ac[o] = __expf(Av * sumdl);
        Sc[o] = h;
    }
}

// ---------------------------------------------------------------- stitch (serial over chunks)
__global__ void __launch_bounds__(256) scan_stitch(
        const float* __restrict__ Ac, const float* __restrict__ Sc,
        float* __restrict__ Hs, int C) {
    int t = blockIdx.x * 256 + threadIdx.x;     // t = gd*16+n
    const float4* Ap = (const float4*)(Ac + (size_t)t * C);
    const float4* Sp = (const float4*)(Sc + (size_t)t * C);
    int gd = t >> 4, n = t & 15;
    float* Ho = Hs + (size_t)gd * C * 16 + n;
    float h = 0.f;
    for (int c4 = 0; c4 < (C >> 2); ++c4) {
        float4 a = Ap[c4], s = Sp[c4];
        Ho[(size_t)(c4 * 4 + 0) * 16] = h; h = fmaf(a.x, h, s.x);
        Ho[(size_t)(c4 * 4 + 1) * 16] = h; h = fmaf(a.y, h, s.y);
        Ho[(size_t)(c4 * 4 + 2) * 16] = h; h = fmaf(a.z, h, s.z);
        Ho[(size_t)(c4 * 4 + 3) * 16] = h; h = fmaf(a.w, h, s.w);
    }
}

// ---------------------------------------------------------------- pass2
__global__ void __launch_bounds__(256) scan_pass2(
        const float* __restrict__ x, const float* __restrict__ xT,
        const float* __restrict__ delta, const float* __restrict__ Bm,
        const float* __restrict__ Cm,
        const float* __restrict__ A_logs, const float* __restrict__ Ds,
        const float* __restrict__ Hs,
        float* __restrict__ ys, int L, int C, int CLOG, int W, int hsh) {
    int idx = blockIdx.x * 256 + threadIdx.x;
    int c = idx & (C - 1);
    int gd = idx >> CLOG;
    int d = gd & 31, bk = gd >> 5;
    int k = bk & 1, b = gd >> 6;
    int l0 = c * CL;
    const float* uptr = (k == 0 ? x : xT) + ((size_t)b * D_INNER + d) * L + l0;
    const float* dp = delta + (size_t)gd * L + l0;
    const float4* Bp4 = (const float4*)(Bm + ((size_t)bk * L + l0) * 16);
    const float4* Cp4 = (const float4*)(Cm + ((size_t)bk * L + l0) * 16);
    const float* Ap = A_logs + (size_t)(gd & 63) * 16;
    float Av[16], h[16];
#pragma unroll
    for (int n = 0; n < 16; ++n) Av[n] = -__expf(Ap[n]);
    const float4* Hp = (const float4*)(Hs + ((size_t)gd * C + c) * 16);
    float4 h0 = Hp[0], h1 = Hp[1], h2 = Hp[2], h3 = Hp[3];
    h[0] = h0.x; h[1] = h0.y; h[2] = h0.z; h[3] = h0.w;
    h[4] = h1.x; h[5] = h1.y; h[6] = h1.z; h[7] = h1.w;
    h[8] = h2.x; h[9] = h2.y; h[10] = h2.z; h[11] = h2.w;
    h[12] = h3.x; h[13] = h3.y; h[14] = h3.z; h[15] = h3.w;
    float Dval = Ds[gd & 63];
    float* yout = ys + (size_t)gd * L;
    int Hm1 = (1 << hsh) - 1;
    for (int j = 0; j < CL; j += 4) {
        float4 dv = *(const float4*)(dp + j);
        float4 uv = *(const float4*)(uptr + j);
        float yb[4];
#pragma unroll
        for (int e = 0; e < 4; ++e) {
            float dl = e == 0 ? dv.x : e == 1 ? dv.y : e == 2 ? dv.z : dv.w;
            float ul = e == 0 ? uv.x : e == 1 ? uv.y : e == 2 ? uv.z : uv.w;
            float du = dl * ul;
            const float4* Bp = Bp4 + (size_t)(j + e) * 4;
            const float4* Cp = Cp4 + (size_t)(j + e) * 4;
            float4 B0 = Bp[0], B1 = Bp[1], B2 = Bp[2], B3 = Bp[3];
            float4 C0 = Cp[0], C1 = Cp[1], C2 = Cp[2], C3 = Cp[3];
            float y = 0.f;
#define STEP(nn, bb, cc) { float a = __expf(dl * Av[nn]); h[nn] = fmaf(a, h[nn], du * (bb)); y = fmaf(h[nn], (cc), y); }
            STEP(0, B0.x, C0.x) STEP(1, B0.y, C0.y) STEP(2, B0.z, C0.z) STEP(3, B0.w, C0.w)
            STEP(4, B1.x, C1.x) STEP(5, B1.y, C1.y) STEP(6, B1.z, C1.z) STEP(7, B1.w, C1.w)
            STEP(8, B2.x, C2.x) STEP(9, B2.y, C2.y) STEP(10, B2.z, C2.z) STEP(11, B2.w, C2.w)
            STEP(12, B3.x, C3.x) STEP(13, B3.y, C3.y) STEP(14, B3.z, C3.z) STEP(15, B3.w, C3.w)
#undef STEP
            y = fmaf(Dval, ul, y);
            if (k == 0) {
                yb[e] = y;
            } else {
                int l = l0 + j + e;
                yout[(l & Hm1) * W + (l >> hsh)] = y;
            }
        }
        if (k == 0)
            *(float4*)(yout + l0 + j) = make_float4(yb[0], yb[1], yb[2], yb[3]);
    }
}

// ---------------------------------------------------------------- combine + LayerNorm(channel)
__global__ void combine_ln_kernel(const float* __restrict__ ys, const float* __restrict__ g,
                                  const float* __restrict__ beta, float* __restrict__ outp, int L) {
    int b = blockIdx.y;
    int l = blockIdx.x * 256 + threadIdx.x;
    const float* y0 = ys + ((size_t)b * KDIRS + 0) * D_INNER * L + l;
    const float* y1 = ys + ((size_t)b * KDIRS + 1) * D_INNER * L + l;
    float v[32]; float sum = 0.f;
#pragma unroll
    for (int d = 0; d < 32; ++d) {
        float t = y0[(size_t)d * L] + y1[(size_t)d * L];
        v[d] = t; sum += t;
    }
    float mu = sum * (1.0f / 32.0f);
    float var = 0.f;
#pragma unroll
    for (int d = 0; d < 32; ++d) { float t = v[d] - mu; var += t * t; }
    var *= (1.0f / 32.0f);
    float inv = 1.0f / sqrtf(var + 1e-5f);
#pragma unroll
    for (int d = 0; d < 32; ++d)
        outp[((size_t)b * D_INNER + d) * L + l] = (v[d] - mu) * inv * g[d] + beta[d];
}

// ---------------------------------------------------------------- host
extern "C" void kernel_launch(void* const* d_in, const int* in_sizes, int n_in,
                              void* d_out, int out_size, void* d_ws, size_t ws_size,
                              hipStream_t stream) {
    const float* out0 = (const float*)d_in[0];
    const float* out1 = (const float*)d_in[1];
    const float* out2 = (const float*)d_in[2];
    const float* out3 = (const float*)d_in[3];
    const float* cw[4] = {(const float*)d_in[4], (const float*)d_in[6],
                          (const float*)d_in[8], (const float*)d_in[10]};
    const float* cb[4] = {(const float*)d_in[5], (const float*)d_in[7],
                          (const float*)d_in[9], (const float*)d_in[11]};
    const float* xpw    = (const float*)d_in[12];
    const float* dtw    = (const float*)d_in[13];
    const float* dtb    = (const float*)d_in[14];
    const float* A_logs = (const float*)d_in[15];
    const float* Ds     = (const float*)d_in[16];
    const float* ln_g   = (const float*)d_in[17];
    const float* ln_b   = (const float*)d_in[18];

    const size_t MF = 1u << 20;     // 1M floats = 4MB
    float* ws    = (float*)d_ws;
    float* fus   = ws;
    float* Hst   = ws + 1 * MF;
    float* up    = ws + 2 * MF;
    float* xbuf  = ws + 3 * MF;
    float* xTbuf = ws + 4 * MF;
    float* delta = ws + 5 * MF;
    float* Bm    = ws + 7 * MF;
    float* Cm    = ws + 8 * MF;
    float* ysbuf = ws + 9 * MF;
    float* Ac    = ws + 11 * MF;
    float* Sc    = ws + 12 * MF;
    float* wT    = ws + 13 * MF;
    float* partial = ws + 14 * MF;

    wtrans_all_kernel<<<(442368 + 255) / 256, 256, 0, stream>>>(cw[0], cw[1], cw[2], cw[3], wT);
    float* wT_f  = wT;
    float* wT_s1 = wT + 221184;
    float* wT_s2 = wT + 340992;
    float* wT_s3 = wT + 405504;

    {
        int Cin = 768, ICS = 8, S = Cin / ICS;
        conv_fus_kernel<<<dim3(2, S, BATCH), 256, 0, stream>>>(out3, Cin, wT_f, partial, ICS);
        size_t planeTotal = (size_t)BATCH * 32 * 256;
        conv_reduce_kernel<<<planeTotal / 256, 256, 0, stream>>>(
            partial, cb[0], fus, S, planeTotal, 256);
    }

    struct Stage { int h, w, H, W, Cf, ICS, hsh; const float* feat; const float* wt; const float* b3; };
    Stage st[3] = {
        {16, 16,  32,  32, 384,  8, 5, out2, wT_s1, cb[1]},
        {32, 32,  64,  64, 192,  8, 6, out1, wT_s2, cb[2]},
        {64, 64, 128, 128,  96, 16, 7, out0, wT_s3, cb[3]},
    };

    for (int i = 0; i < 3; ++i) {
        int H = st[i].H, Wv = st[i].W;
        int L = H * Wv;
        int h = st[i].h, w = st[i].w;
        int total = BATCH * 32 * H * Wv;
        upsample_kernel<<<total / 256, 256, 0, stream>>>(fus, up, h, w, H, Wv, total);

        int Cin = 32 + st[i].Cf;
        int ICS = st[i].ICS, S = Cin / ICS;    // 52 / 28 / 8
        int tilesX = Wv / 32, tiles = (H / 16) * tilesX;
        conv_stage_kernel<<<dim3(tiles, S, BATCH), 512, 0, stream>>>(
            up, st[i].feat, st[i].Cf, st[i].wt, partial, H, Wv, tilesX, ICS);

        reduce_transpose_kernel<<<dim3((H / 32) * tilesX, BATCH * 32), 1024, 0, stream>>>(
            partial, cb[i + 1], xbuf, xTbuf, S, H, Wv, tilesX);

        int C = L / CL;                        // 32 / 128 / 512
        int CLOG = (C == 32) ? 5 : (C == 128) ? 7 : 9;
        proj_scan1_kernel<<<dim3(L / 64, KDIRS, BATCH), 256, 0, stream>>>(
            xbuf, xTbuf, xpw, dtw, dtb, A_logs, delta, Bm, Cm, Ac, Sc, L, C);

        scan_stitch<<<8, 256, 0, stream>>>(Ac, Sc, Hst, C);
        scan_pass2<<<(128 * C) / 256, 256, 0, stream>>>(
            xbuf, xTbuf, delta, Bm, Cm, A_logs, Ds, Hst, ysbuf, L, C, CLOG, Wv, st[i].hsh);

        float* dst = (i == 2) ? (float*)d_out : fus;
        combine_ln_kernel<<<dim3(L / 256, BATCH), 256, 0, stream>>>(ysbuf, ln_g, ln_b, dst, L);
    }
}